// Round 5
// baseline (365.965 us; speedup 1.0000x reference)
//
#include <hip/hip_runtime.h>

// MultiResolutionHashEncoding, space-phased across XCDs.
// One gather kernel: blocks with (blockIdx&7)==i handle level pair {i,15-i}
// for ALL points, time-phased (level A for all its points, then level B), so
// each XCD's 4 MiB L2 holds ~one level slice at a time. No grid sync needed:
// per-level ws slabs are disjoint, so the XCD mapping is perf-only.
// Fine levels use nontemporal gathers (L1 hit rate ~0 at 4 MiB/slice).
//
// Scalings floor(16*growth^l) with f32 semantics of the reference
// (growth rounds DOWN in f32 => level 15 scaling is 2047, not 2048).
__device__ __constant__ float c_scal[16] = {
    16.f, 22.f, 30.f, 42.f, 58.f, 80.f, 111.f, 153.f,
    212.f, 294.f, 406.f, 561.f, 776.f, 1072.f, 1482.f, 2047.f
};

#define TBL_T 524288u   // 2^19 entries per level
#define NPTS  524288u

template <bool NT>
__device__ __forceinline__ float2 level_feat(
        const float2* __restrict__ tbl, float px, float py, float pz,
        float s, unsigned base) {
    float sx = px * s, sy = py * s, sz = pz * s;
    float cx = floorf(sx), cy = floorf(sy), cz = floorf(sz);
    float fx = sx - cx, fy = sy - cy, fz = sz - cz;

    unsigned ux = (unsigned)cx, uy = (unsigned)cy, uz = (unsigned)cz;

    unsigned hx0 = ux,               hx1 = ux + 1u;
    unsigned hy0 = uy * 2654435761u, hy1 = (uy + 1u) * 2654435761u;
    unsigned hz0 = uz * 805459861u,  hz1 = (uz + 1u) * 805459861u;

    unsigned idx[8];
#pragma unroll
    for (int i = 0; i < 8; ++i) {
        unsigned h = ((i & 4) ? hx1 : hx0) ^ ((i & 2) ? hy1 : hy0)
                   ^ ((i & 1) ? hz1 : hz0);
        idx[i] = (h & (TBL_T - 1u)) + base;
    }

    float2 v[8];
#pragma unroll
    for (int i = 0; i < 8; ++i) {
        if (NT) {
            unsigned long long u = __builtin_nontemporal_load(
                reinterpret_cast<const unsigned long long*>(tbl) + idx[i]);
            __builtin_memcpy(&v[i], &u, 8);
        } else {
            v[i] = tbl[idx[i]];
        }
    }

    float wx1 = fx, wx0 = 1.f - fx;
    float wy1 = fy, wy0 = 1.f - fy;
    float wz1 = fz, wz0 = 1.f - fz;

    float o0 = 0.f, o1 = 0.f;
#pragma unroll
    for (int i = 0; i < 8; ++i) {
        float w = (((i & 4) ? wx1 : wx0) * ((i & 2) ? wy1 : wy0))
                * ((i & 1) ? wz1 : wz0);
        o0 += v[i].x * w;
        o1 += v[i].y * w;
    }
    return make_float2(o0, o1);
}

__device__ __forceinline__ void do_level(
        const float* __restrict__ x, const float2* __restrict__ tbl,
        float2* __restrict__ ws, int l, unsigned local) {
    float s = c_scal[l];
    unsigned base = (unsigned)l * TBL_T;
    bool fine = (l >= 3);
    // 65536 threads per XCD-group sweep all 524288 points in 8 strides.
#pragma unroll 2
    for (unsigned q = 0; q < 8; ++q) {
        unsigned p = q * 65536u + local * 256u + threadIdx.x;
        float px = x[p * 3 + 0], py = x[p * 3 + 1], pz = x[p * 3 + 2];
        float2 f = fine ? level_feat<true >(tbl, px, py, pz, s, base)
                        : level_feat<false>(tbl, px, py, pz, s, base);
        ws[(size_t)l * NPTS + p] = f;
    }
}

__global__ __launch_bounds__(256, 8) void hashenc_xcd(
        const float* __restrict__ x,
        const float2* __restrict__ tbl,
        float2* __restrict__ ws) {
    unsigned b     = blockIdx.x;   // 0..2047
    unsigned xcd   = b & 7u;       // XCD heuristic (perf only)
    unsigned local = b >> 3;       // 0..255 within group

    // level pair {xcd, 15-xcd}: balanced coarse+fine per XCD,
    // time-phased so one 4 MiB slice is active per XCD L2.
    do_level(x, tbl, ws, (int)xcd,      local);
    do_level(x, tbl, ws, 15 - (int)xcd, local);
}

// ws[16][NPTS] float2  ->  out[NPTS][16] float2 (128 B contiguous per point)
__global__ __launch_bounds__(256) void hashenc_transpose(
        const float2* __restrict__ ws,
        float4* __restrict__ out) {
    unsigned p = blockIdx.x * 256u + threadIdx.x;
    float2 v[16];
#pragma unroll
    for (int l = 0; l < 16; ++l) v[l] = ws[(size_t)l * NPTS + p];
    float4* dst = out + (size_t)p * 8u;
#pragma unroll
    for (int q = 0; q < 8; ++q)
        dst[q] = make_float4(v[2 * q].x, v[2 * q].y, v[2 * q + 1].x, v[2 * q + 1].y);
}

// Fallback (ws too small): single kernel, one thread per point.
__global__ __launch_bounds__(256) void hashenc_mono(
        const float* __restrict__ x,
        const float2* __restrict__ tbl,
        float4* __restrict__ out) {
    unsigned p = blockIdx.x * 256u + threadIdx.x;
    float px = x[p * 3 + 0], py = x[p * 3 + 1], pz = x[p * 3 + 2];
    float o[32];
#pragma unroll
    for (int l = 0; l < 16; ++l) {
        float2 f = level_feat<false>(tbl, px, py, pz, c_scal[l],
                                     (unsigned)l * TBL_T);
        o[2 * l] = f.x; o[2 * l + 1] = f.y;
        __syncthreads();
    }
    float4* dst = out + (size_t)p * 8u;
#pragma unroll
    for (int q = 0; q < 8; ++q)
        dst[q] = make_float4(o[4 * q], o[4 * q + 1], o[4 * q + 2], o[4 * q + 3]);
}

extern "C" void kernel_launch(void* const* d_in, const int* in_sizes, int n_in,
                              void* d_out, int out_size, void* d_ws, size_t ws_size,
                              hipStream_t stream) {
    const float*  x   = (const float*)d_in[0];
    const float2* tbl = (const float2*)d_in[1];   // [L*T][F=2] floats
    const size_t need = (size_t)16 * NPTS * sizeof(float2);  // 64 MiB

    const unsigned block = 256u;
    const unsigned grid  = NPTS / block;          // 2048 blocks

    if (ws_size >= need) {
        float2* ws = (float2*)d_ws;
        hashenc_xcd<<<grid, block, 0, stream>>>(x, tbl, ws);
        hashenc_transpose<<<grid, block, 0, stream>>>(ws, (float4*)d_out);
    } else {
        hashenc_mono<<<grid, block, 0, stream>>>(x, tbl, (float4*)d_out);
    }
}

// Round 6
// 343.206 us; speedup vs baseline: 1.0663x; 1.0663x over previous
//
#include <hip/hip_runtime.h>

// MultiResolutionHashEncoding, level-phased via separate launches (hard
// device-wide barrier per level => one 4 MiB slice active per XCD L2), with
// TWO points per thread so each wave keeps 16 gathers in flight (testing the
// latency-bound hypothesis: R4 showed 0.33 gathers/cy/CU with 8/wave).
//
// Scalings floor(16*growth^l) with f32 semantics of the reference
// (growth rounds DOWN in f32 => level 15 scaling is 2047, not 2048).
__device__ __constant__ float c_scal[16] = {
    16.f, 22.f, 30.f, 42.f, 58.f, 80.f, 111.f, 153.f,
    212.f, 294.f, 406.f, 561.f, 776.f, 1072.f, 1482.f, 2047.f
};

#define TBL_T 524288u   // 2^19 entries per level
#define NPTS  524288u
#define HALF  262144u

struct PtState {
    float fx, fy, fz;
    unsigned idx[8];
};

__device__ __forceinline__ void prep(float px, float py, float pz,
                                     float s, unsigned base, PtState& st) {
    float sx = px * s, sy = py * s, sz = pz * s;
    float cx = floorf(sx), cy = floorf(sy), cz = floorf(sz);
    st.fx = sx - cx; st.fy = sy - cy; st.fz = sz - cz;
    unsigned ux = (unsigned)cx, uy = (unsigned)cy, uz = (unsigned)cz;
    unsigned hx0 = ux,               hx1 = ux + 1u;
    unsigned hy0 = uy * 2654435761u, hy1 = (uy + 1u) * 2654435761u;
    unsigned hz0 = uz * 805459861u,  hz1 = (uz + 1u) * 805459861u;
#pragma unroll
    for (int i = 0; i < 8; ++i) {
        unsigned h = ((i & 4) ? hx1 : hx0) ^ ((i & 2) ? hy1 : hy0)
                   ^ ((i & 1) ? hz1 : hz0);
        st.idx[i] = (h & (TBL_T - 1u)) + base;
    }
}

__device__ __forceinline__ float2 reduce8(const PtState& st, const float2* v) {
    float wx1 = st.fx, wx0 = 1.f - st.fx;
    float wy1 = st.fy, wy0 = 1.f - st.fy;
    float wz1 = st.fz, wz0 = 1.f - st.fz;
    float o0 = 0.f, o1 = 0.f;
#pragma unroll
    for (int i = 0; i < 8; ++i) {
        float w = (((i & 4) ? wx1 : wx0) * ((i & 2) ? wy1 : wy0))
                * ((i & 1) ? wz1 : wz0);
        o0 += v[i].x * w;
        o1 += v[i].y * w;
    }
    return make_float2(o0, o1);
}

// One fine level per launch; 2 points per thread, 16 gathers in flight.
__global__ __launch_bounds__(256) void hashenc_level(
        const float* __restrict__ x,
        const float2* __restrict__ tbl,
        float2* __restrict__ ws,
        int l) {
    unsigned t  = blockIdx.x * 256u + threadIdx.x;   // 0..262143
    unsigned pA = t, pB = t + HALF;

    float ax = x[pA * 3 + 0], ay = x[pA * 3 + 1], az = x[pA * 3 + 2];
    float bx = x[pB * 3 + 0], by = x[pB * 3 + 1], bz = x[pB * 3 + 2];

    float s = c_scal[l];
    unsigned base = (unsigned)l * TBL_T;

    PtState A, B;
    prep(ax, ay, az, s, base, A);
    prep(bx, by, bz, s, base, B);

    float2 va[8], vb[8];
#pragma unroll
    for (int i = 0; i < 8; ++i) va[i] = tbl[A.idx[i]];
#pragma unroll
    for (int i = 0; i < 8; ++i) vb[i] = tbl[B.idx[i]];

    float2 fa = reduce8(A, va);
    float2 fb = reduce8(B, vb);

    ws[(size_t)l * NPTS + pA] = fa;
    ws[(size_t)l * NPTS + pB] = fb;
}

// Levels 0..4 fused (combined slice footprint ~2.6 MB); 2 points per thread.
__global__ __launch_bounds__(256) void hashenc_coarse(
        const float* __restrict__ x,
        const float2* __restrict__ tbl,
        float2* __restrict__ ws) {
    unsigned t  = blockIdx.x * 256u + threadIdx.x;
    unsigned pA = t, pB = t + HALF;

    float ax = x[pA * 3 + 0], ay = x[pA * 3 + 1], az = x[pA * 3 + 2];
    float bx = x[pB * 3 + 0], by = x[pB * 3 + 1], bz = x[pB * 3 + 2];

#pragma unroll
    for (int l = 0; l < 5; ++l) {
        float s = c_scal[l];
        unsigned base = (unsigned)l * TBL_T;
        PtState A, B;
        prep(ax, ay, az, s, base, A);
        prep(bx, by, bz, s, base, B);
        float2 va[8], vb[8];
#pragma unroll
        for (int i = 0; i < 8; ++i) va[i] = tbl[A.idx[i]];
#pragma unroll
        for (int i = 0; i < 8; ++i) vb[i] = tbl[B.idx[i]];
        ws[(size_t)l * NPTS + pA] = reduce8(A, va);
        ws[(size_t)l * NPTS + pB] = reduce8(B, vb);
    }
}

// ws[16][NPTS] float2  ->  out[NPTS][16] float2 (128 B contiguous per point)
__global__ __launch_bounds__(256) void hashenc_transpose(
        const float2* __restrict__ ws,
        float4* __restrict__ out) {
    unsigned p = blockIdx.x * 256u + threadIdx.x;
    float2 v[16];
#pragma unroll
    for (int l = 0; l < 16; ++l) v[l] = ws[(size_t)l * NPTS + p];
    float4* dst = out + (size_t)p * 8u;
#pragma unroll
    for (int q = 0; q < 8; ++q)
        dst[q] = make_float4(v[2 * q].x, v[2 * q].y, v[2 * q + 1].x, v[2 * q + 1].y);
}

// Fallback (ws too small): single kernel, one thread per point.
__global__ __launch_bounds__(256) void hashenc_mono(
        const float* __restrict__ x,
        const float2* __restrict__ tbl,
        float4* __restrict__ out) {
    unsigned p = blockIdx.x * 256u + threadIdx.x;
    float px = x[p * 3 + 0], py = x[p * 3 + 1], pz = x[p * 3 + 2];
    float o[32];
#pragma unroll
    for (int l = 0; l < 16; ++l) {
        PtState st;
        prep(px, py, pz, c_scal[l], (unsigned)l * TBL_T, st);
        float2 v[8];
#pragma unroll
        for (int i = 0; i < 8; ++i) v[i] = tbl[st.idx[i]];
        float2 f = reduce8(st, v);
        o[2 * l] = f.x; o[2 * l + 1] = f.y;
        __syncthreads();
    }
    float4* dst = out + (size_t)p * 8u;
#pragma unroll
    for (int q = 0; q < 8; ++q)
        dst[q] = make_float4(o[4 * q], o[4 * q + 1], o[4 * q + 2], o[4 * q + 3]);
}

extern "C" void kernel_launch(void* const* d_in, const int* in_sizes, int n_in,
                              void* d_out, int out_size, void* d_ws, size_t ws_size,
                              hipStream_t stream) {
    const float*  x   = (const float*)d_in[0];
    const float2* tbl = (const float2*)d_in[1];   // [L*T][F=2] floats
    const size_t need = (size_t)16 * NPTS * sizeof(float2);  // 64 MiB

    if (ws_size >= need) {
        float2* ws = (float2*)d_ws;
        const unsigned gGather = HALF / 256u;   // 1024 blocks (2 pts/thread)
        const unsigned gFull   = NPTS / 256u;   // 2048 blocks

        hashenc_coarse<<<gGather, 256, 0, stream>>>(x, tbl, ws);
        for (int l = 5; l < 16; ++l)
            hashenc_level<<<gGather, 256, 0, stream>>>(x, tbl, ws, l);
        hashenc_transpose<<<gFull, 256, 0, stream>>>(ws, (float4*)d_out);
    } else {
        hashenc_mono<<<NPTS / 256u, 256, 0, stream>>>(x, tbl, (float4*)d_out);
    }
}

// Round 7
// 244.267 us; speedup vs baseline: 1.4982x; 1.4050x over previous
//
#include <hip/hip_runtime.h>

// MultiResolutionHashEncoding, level-phased via separate launches (hard
// device-wide barrier per level => one 4 MiB slice active per XCD L2).
// KEY TRICK: PRIMES[0]==1, so corner pairs (ix=0 -> ix=1) map to table slots
// h and h^1 when ux is even -> ONE aligned float4 load covers both corners.
// Halves gather requests for even-ux points: avg 6 requests/point-level
// instead of 8 (the kernel is MSHR/request-rate bound at ~0.33/cy/CU).
//
// Scalings floor(16*growth^l) with f32 semantics of the reference
// (growth rounds DOWN in f32 => level 15 scaling is 2047, not 2048).
__device__ __constant__ float c_scal[16] = {
    16.f, 22.f, 30.f, 42.f, 58.f, 80.f, 111.f, 153.f,
    212.f, 294.f, 406.f, 561.f, 776.f, 1072.f, 1482.f, 2047.f
};

#define TBL_T 524288u   // 2^19 entries per level
#define NPTS  524288u
#define TMASK (TBL_T - 1u)

// Compute one level's feature for one point. Parity-split gather.
__device__ __forceinline__ float2 level_feat(
        const float2* __restrict__ tbl, float px, float py, float pz,
        float s, unsigned base) {
    float sx = px * s, sy = py * s, sz = pz * s;
    float cx = floorf(sx), cy = floorf(sy), cz = floorf(sz);
    float fx = sx - cx, fy = sy - cy, fz = sz - cz;

    unsigned ux = (unsigned)cx, uy = (unsigned)cy, uz = (unsigned)cz;

    unsigned hy0 = uy * 2654435761u, hy1 = (uy + 1u) * 2654435761u;
    unsigned hz0 = uz * 805459861u,  hz1 = (uz + 1u) * 805459861u;

    float wx1 = fx, wx0 = 1.f - fx;
    float wy1 = fy, wy0 = 1.f - fy;
    float wz1 = fz, wz0 = 1.f - fz;

    // per-(iy,iz) combined weights; j = (iy<<1)|iz
    float wyz[4] = { wy0 * wz0, wy0 * wz1, wy1 * wz0, wy1 * wz1 };
    unsigned hyz[4] = { hy0 ^ hz0, hy0 ^ hz1, hy1 ^ hz0, hy1 ^ hz1 };

    float o0 = 0.f, o1 = 0.f;

    if ((ux & 1u) == 0u) {
        // even ux: corners (0,iy,iz) and (1,iy,iz) at slots {2k,2k+1}
        float4 f[4];
#pragma unroll
        for (int j = 0; j < 4; ++j) {
            unsigned idx0 = ((ux ^ hyz[j]) & TMASK) + base;   // ix=0 slot
            f[j] = *reinterpret_cast<const float4*>(
                       reinterpret_cast<const float*>(tbl) + ((idx0 & ~1u) << 1));
        }
#pragma unroll
        for (int j = 0; j < 4; ++j) {
            unsigned idx0 = ((ux ^ hyz[j]) & TMASK) + base;
            bool hi0 = (idx0 & 1u) != 0u;   // ix=0 in hi half?
            float c0x = hi0 ? f[j].z : f[j].x;
            float c0y = hi0 ? f[j].w : f[j].y;
            float c1x = hi0 ? f[j].x : f[j].z;
            float c1y = hi0 ? f[j].y : f[j].w;
            o0 += c0x * (wx0 * wyz[j]) + c1x * (wx1 * wyz[j]);
            o1 += c0y * (wx0 * wyz[j]) + c1y * (wx1 * wyz[j]);
        }
    } else {
        // odd ux: slots unrelated, 8 separate float2 gathers
        unsigned ux1 = ux + 1u;
        float2 v0[4], v1[4];
#pragma unroll
        for (int j = 0; j < 4; ++j) {
            v0[j] = tbl[((ux  ^ hyz[j]) & TMASK) + base];
            v1[j] = tbl[((ux1 ^ hyz[j]) & TMASK) + base];
        }
#pragma unroll
        for (int j = 0; j < 4; ++j) {
            o0 += v0[j].x * (wx0 * wyz[j]) + v1[j].x * (wx1 * wyz[j]);
            o1 += v0[j].y * (wx0 * wyz[j]) + v1[j].y * (wx1 * wyz[j]);
        }
    }
    return make_float2(o0, o1);
}

// One fine level per launch.
__global__ __launch_bounds__(256) void hashenc_level(
        const float* __restrict__ x,
        const float2* __restrict__ tbl,
        float2* __restrict__ ws,
        int l) {
    unsigned p = blockIdx.x * 256u + threadIdx.x;
    float px = x[p * 3 + 0], py = x[p * 3 + 1], pz = x[p * 3 + 2];
    ws[(size_t)l * NPTS + p] =
        level_feat(tbl, px, py, pz, c_scal[l], (unsigned)l * TBL_T);
}

// Levels 0..4 fused (combined slice footprint ~2.6 MB).
__global__ __launch_bounds__(256) void hashenc_coarse(
        const float* __restrict__ x,
        const float2* __restrict__ tbl,
        float2* __restrict__ ws) {
    unsigned p = blockIdx.x * 256u + threadIdx.x;
    float px = x[p * 3 + 0], py = x[p * 3 + 1], pz = x[p * 3 + 2];
#pragma unroll
    for (int l = 0; l < 5; ++l)
        ws[(size_t)l * NPTS + p] =
            level_feat(tbl, px, py, pz, c_scal[l], (unsigned)l * TBL_T);
}

// ws[16][NPTS] float2  ->  out[NPTS][16] float2 (128 B contiguous per point)
__global__ __launch_bounds__(256) void hashenc_transpose(
        const float2* __restrict__ ws,
        float4* __restrict__ out) {
    unsigned p = blockIdx.x * 256u + threadIdx.x;
    float2 v[16];
#pragma unroll
    for (int l = 0; l < 16; ++l) v[l] = ws[(size_t)l * NPTS + p];
    float4* dst = out + (size_t)p * 8u;
#pragma unroll
    for (int q = 0; q < 8; ++q)
        dst[q] = make_float4(v[2 * q].x, v[2 * q].y, v[2 * q + 1].x, v[2 * q + 1].y);
}

// Fallback (ws too small): single kernel, one thread per point.
__global__ __launch_bounds__(256) void hashenc_mono(
        const float* __restrict__ x,
        const float2* __restrict__ tbl,
        float4* __restrict__ out) {
    unsigned p = blockIdx.x * 256u + threadIdx.x;
    float px = x[p * 3 + 0], py = x[p * 3 + 1], pz = x[p * 3 + 2];
    float o[32];
#pragma unroll
    for (int l = 0; l < 16; ++l) {
        float2 f = level_feat(tbl, px, py, pz, c_scal[l], (unsigned)l * TBL_T);
        o[2 * l] = f.x; o[2 * l + 1] = f.y;
        __syncthreads();
    }
    float4* dst = out + (size_t)p * 8u;
#pragma unroll
    for (int q = 0; q < 8; ++q)
        dst[q] = make_float4(o[4 * q], o[4 * q + 1], o[4 * q + 2], o[4 * q + 3]);
}

extern "C" void kernel_launch(void* const* d_in, const int* in_sizes, int n_in,
                              void* d_out, int out_size, void* d_ws, size_t ws_size,
                              hipStream_t stream) {
    const float*  x   = (const float*)d_in[0];
    const float2* tbl = (const float2*)d_in[1];   // [L*T][F=2] floats
    const size_t need = (size_t)16 * NPTS * sizeof(float2);  // 64 MiB

    const unsigned block = 256u;
    const unsigned grid  = NPTS / block;          // 2048 blocks

    if (ws_size >= need) {
        float2* ws = (float2*)d_ws;
        hashenc_coarse<<<grid, block, 0, stream>>>(x, tbl, ws);
        for (int l = 5; l < 16; ++l)
            hashenc_level<<<grid, block, 0, stream>>>(x, tbl, ws, l);
        hashenc_transpose<<<grid, block, 0, stream>>>(ws, (float4*)d_out);
    } else {
        hashenc_mono<<<grid, block, 0, stream>>>(x, tbl, (float4*)d_out);
    }
}